// Round 1
// baseline (149.372 us; speedup 1.0000x reference)
//
#include <hip/hip_runtime.h>
#include <hip/hip_bf16.h>

typedef __bf16 bf16x8 __attribute__((ext_vector_type(8)));
typedef float  f32x4  __attribute__((ext_vector_type(4)));

__device__ __forceinline__ unsigned short f2bf(float f) {
    unsigned int u = __builtin_bit_cast(unsigned int, f);
    unsigned int r = (u + 0x7fffu + ((u >> 16) & 1u)) >> 16;
    return (unsigned short)r;
}

// ---------------------------------------------------------------------------
// Prep: s_bf[n][u] = bf16(node_vec[n][u]) (u<128);
//       W1B[w*32+v][u] = bf16(W1s[u][v][w]);  W2B[w2*32+v][u] = bf16(W2[u][v][w2])
// ---------------------------------------------------------------------------
__global__ __launch_bounds__(256) void prep_kernel(
    const float* __restrict__ node_vec, const float* __restrict__ W1s,
    const float* __restrict__ W2, unsigned short* __restrict__ s_bf,
    unsigned short* __restrict__ W1B, unsigned short* __restrict__ W2B)
{
    int tid = blockIdx.x * 256 + threadIdx.x;
    if (tid < 131072) {
        // s_bf: 8192 x 128, 8 elements per thread
        int n = tid >> 4, c8 = tid & 15;
        const float4* p = (const float4*)(node_vec + n * 480 + c8 * 8);
        float4 a = p[0], b = p[1];
        unsigned short o[8] = { f2bf(a.x), f2bf(a.y), f2bf(a.z), f2bf(a.w),
                                f2bf(b.x), f2bf(b.y), f2bf(b.z), f2bf(b.w) };
        *(uint4*)(s_bf + n * 128 + c8 * 8) = *(const uint4*)o;
    } else if (tid < 262144) {
        int j = tid - 131072;              // (u, v, w4): 128*32*32
        int u = j >> 10, v = (j >> 5) & 31, w4 = j & 31;
        float4 f = *(const float4*)(W1s + (u * 32 + v) * 128 + w4 * 4);
        int w0 = w4 * 4;
        W1B[((w0 + 0) * 32 + v) * 128 + u] = f2bf(f.x);
        W1B[((w0 + 1) * 32 + v) * 128 + u] = f2bf(f.y);
        W1B[((w0 + 2) * 32 + v) * 128 + u] = f2bf(f.z);
        W1B[((w0 + 3) * 32 + v) * 128 + u] = f2bf(f.w);
    } else if (tid < 294912) {
        int j = tid - 262144;              // (u, v, w4): 128*32*8
        int u = j >> 8, v = (j >> 3) & 31, w4 = j & 7;
        float4 f = *(const float4*)(W2 + (u * 32 + v) * 32 + w4 * 4);
        int w0 = w4 * 4;
        W2B[((w0 + 0) * 32 + v) * 128 + u] = f2bf(f.x);
        W2B[((w0 + 1) * 32 + v) * 128 + u] = f2bf(f.y);
        W2B[((w0 + 2) * 32 + v) * 128 + u] = f2bf(f.z);
        W2B[((w0 + 3) * 32 + v) * 128 + u] = f2bf(f.w);
    }
}

// ---------------------------------------------------------------------------
// Fused GEMM + v-contraction.
//   G[n, c] = sum_u A[n,u] * B[c,u]   (M=8192, K=128, tile 128x128)
//   out[n, w] = f( sum_v attr[n,v] * G[n, w*32+v] / 64 + bias[w] )
// SILU=1: f = silu, store bf16 [n][128]; SILU=0: identity, store f32 [n][32]
// ---------------------------------------------------------------------------
template <int SILU>
__global__ __launch_bounds__(256) void tp_gemm(
    const unsigned short* __restrict__ Abf,   // [8192][128] bf16
    const unsigned short* __restrict__ Bbf,   // [NC][128]  bf16
    const float* __restrict__ attr,           // [8192][32] f32
    const float* __restrict__ bias,
    void* __restrict__ out)
{
    __shared__ alignas(16) unsigned char smem[128 * 136 * 2 * 2];  // 69632 B
    unsigned short* A_lds = (unsigned short*)smem;                 // [128][136]
    unsigned short* B_lds = A_lds + 128 * 136;                     // [128][136]
    float* C_lds = (float*)smem;                                   // alias, stride 132

    const int n0 = blockIdx.x * 128;
    const int c0 = blockIdx.y * 128;
    const int t  = threadIdx.x;

    // Stage A and B tiles (bf16, padded rows: 136 elements)
    #pragma unroll
    for (int i = 0; i < 8; ++i) {
        int s = t + 256 * i;
        int r = s >> 4, c8 = s & 15;
        uint4 d = *(const uint4*)(Abf + (n0 + r) * 128 + c8 * 8);
        *(uint4*)(A_lds + r * 136 + c8 * 8) = d;
    }
    #pragma unroll
    for (int i = 0; i < 8; ++i) {
        int s = t + 256 * i;
        int r = s >> 4, c8 = s & 15;
        uint4 d = *(const uint4*)(Bbf + (c0 + r) * 128 + c8 * 8);
        *(uint4*)(B_lds + r * 136 + c8 * 8) = d;
    }
    __syncthreads();

    const int wv = t >> 6;      // wave 0..3 -> rows 32*wv..+32
    const int l  = t & 63;
    const int lr = l & 15;
    const int q  = l >> 4;

    f32x4 acc[2][8];
    #pragma unroll
    for (int a = 0; a < 2; ++a)
        #pragma unroll
        for (int b = 0; b < 8; ++b) acc[a][b] = f32x4{0.f, 0.f, 0.f, 0.f};

    #pragma unroll
    for (int ks = 0; ks < 4; ++ks) {
        bf16x8 fa[2], fb[8];
        #pragma unroll
        for (int rt = 0; rt < 2; ++rt) {
            int row = 32 * wv + 16 * rt + lr;
            fa[rt] = *(const bf16x8*)(A_lds + row * 136 + ks * 32 + q * 8);
        }
        #pragma unroll
        for (int ct = 0; ct < 8; ++ct) {
            int col = 16 * ct + lr;
            fb[ct] = *(const bf16x8*)(B_lds + col * 136 + ks * 32 + q * 8);
        }
        #pragma unroll
        for (int rt = 0; rt < 2; ++rt)
            #pragma unroll
            for (int ct = 0; ct < 8; ++ct)
                acc[rt][ct] = __builtin_amdgcn_mfma_f32_16x16x32_bf16(
                    fa[rt], fb[ct], acc[rt][ct], 0, 0, 0);
    }
    __syncthreads();   // all waves done with A_lds/B_lds before aliasing as C_lds

    // Spill C tiles to LDS (f32, stride 132). C layout: col=lane&15, row=q*4+reg
    #pragma unroll
    for (int rt = 0; rt < 2; ++rt)
        #pragma unroll
        for (int ct = 0; ct < 8; ++ct)
            #pragma unroll
            for (int rg = 0; rg < 4; ++rg) {
                int row = 32 * wv + 16 * rt + q * 4 + rg;
                int col = 16 * ct + lr;
                C_lds[row * 132 + col] = acc[rt][ct][rg];
            }
    __syncthreads();

    // v-contraction: 512 outputs (128 n x 4 w), 2 per thread
    #pragma unroll
    for (int rep = 0; rep < 2; ++rep) {
        int idx = t + 256 * rep;
        int n = idx & 127, w4 = idx >> 7;
        const float4* ap = (const float4*)(attr + (size_t)(n0 + n) * 32);
        const float4* cp = (const float4*)(C_lds + n * 132 + w4 * 32);
        float s = 0.f;
        #pragma unroll
        for (int jj = 0; jj < 8; ++jj) {
            float4 a4 = ap[jj];
            float4 c4 = cp[jj];
            s += a4.x * c4.x + a4.y * c4.y + a4.z * c4.z + a4.w * c4.w;
        }
        int wg = (c0 >> 5) + w4;                  // global w index
        float val = s * 0.015625f + bias[wg];     // * 1/64
        if (SILU) {
            float act = val / (1.f + __expf(-val));
            ((unsigned short*)out)[(size_t)(n0 + n) * 128 + wg] = f2bf(act);
        } else {
            ((float*)out)[(size_t)(n0 + n) * 32 + wg] = val;
        }
    }
}

// ---------------------------------------------------------------------------
// Head: out[n] = silu(h @ W3/sqrt(32) + b3) @ W4/sqrt(32) + b4
// One lane per (n, j), shuffle-reduce over j.
// ---------------------------------------------------------------------------
__global__ __launch_bounds__(256) void head_kernel(
    const float* __restrict__ h, const float* __restrict__ W3,
    const float* __restrict__ b3, const float* __restrict__ W4,
    const float* __restrict__ b4, float* __restrict__ out)
{
    int tid = blockIdx.x * 256 + threadIdx.x;
    int n = tid >> 5, j = tid & 31;
    const float inv = 0.17677669529663687f;  // 1/sqrt(32)
    const float* hr = h + (size_t)n * 32;
    float acc = 0.f;
    #pragma unroll
    for (int i = 0; i < 32; ++i) acc += hr[i] * W3[i * 32 + j];
    float tv = acc * inv + b3[j];
    float g  = tv / (1.f + __expf(-tv));
    float p  = g * W4[j] * inv;
    #pragma unroll
    for (int m = 16; m >= 1; m >>= 1) p += __shfl_xor(p, m, 32);
    if (j == 0) out[n] = p + b4[0];
}

// ---------------------------------------------------------------------------
extern "C" void kernel_launch(void* const* d_in, const int* in_sizes, int n_in,
                              void* d_out, int out_size, void* d_ws, size_t ws_size,
                              hipStream_t stream)
{
    const float* node_vec = (const float*)d_in[0];
    const float* attr     = (const float*)d_in[1];
    const float* W1s      = (const float*)d_in[2];
    const float* b1s      = (const float*)d_in[3];
    // d_in[4..7] = W1g,b1g,W1v1,W1v2 : dead code w.r.t. pred_energy
    const float* W2       = (const float*)d_in[8];
    const float* b2       = (const float*)d_in[9];
    const float* W3       = (const float*)d_in[10];
    const float* b3       = (const float*)d_in[11];
    const float* W4       = (const float*)d_in[12];
    const float* b4       = (const float*)d_in[13];
    float* out = (float*)d_out;

    char* ws = (char*)d_ws;
    unsigned short* s_bf  = (unsigned short*)(ws);                 // 8192*128*2 = 2 MiB
    unsigned short* W1B   = (unsigned short*)(ws + 2097152);       // 4096*128*2 = 1 MiB
    unsigned short* W2B   = (unsigned short*)(ws + 3145728);       // 1024*128*2 = 256 KiB
    unsigned short* s_act = (unsigned short*)(ws + 3407872);       // 8192*128*2 = 2 MiB
    float*          h     = (float*)(ws + 5505024);                // 8192*32*4  = 1 MiB

    prep_kernel<<<1152, 256, 0, stream>>>(node_vec, W1s, W2, s_bf, W1B, W2B);
    tp_gemm<1><<<dim3(64, 32), 256, 0, stream>>>(s_bf, W1B, attr, b1s, (void*)s_act);
    tp_gemm<0><<<dim3(64, 8), 256, 0, stream>>>(s_act, W2B, attr, b2, (void*)h);
    head_kernel<<<1024, 256, 0, stream>>>(h, W3, b3, W4, b4, out);
}

// Round 2
// 117.325 us; speedup vs baseline: 1.2731x; 1.2731x over previous
//
#include <hip/hip_runtime.h>

typedef _Float16 f16;
typedef f16 f16x8 __attribute__((ext_vector_type(8)));
typedef f16 f16x4 __attribute__((ext_vector_type(4)));
typedef f16 f16x2 __attribute__((ext_vector_type(2)));
typedef float f32x4 __attribute__((ext_vector_type(4)));

// ---------------------------------------------------------------------------
// Prep:
//   s_f16[n][u]    = f16(node_vec[n][u])          (8192 x 128)
//   attr_f16[n][v] = f16(node_embedding[n][v])    (8192 x 32)
//   W1P[u][w][v]   = f16(W1s[u][v][w])            (128 x 128 x 32)
//   W2P[u][w2][v]  = f16(W2[u][v][w2])            (128 x 32 x 32)
// Transposes go through LDS so both reads and writes are coalesced.
// ---------------------------------------------------------------------------
__global__ __launch_bounds__(256) void prep_kernel(
    const float* __restrict__ node_vec, const float* __restrict__ attr,
    const float* __restrict__ W1s, const float* __restrict__ W2,
    f16* __restrict__ s_f16, f16* __restrict__ attr_f16,
    f16* __restrict__ W1P, f16* __restrict__ W2P)
{
    __shared__ f16 T[32 * 36];
    const int b = blockIdx.x, t = threadIdx.x;

    if (b < 640) {
        // weight transpose: [u][v][w] -> [u][w][v]
        const float* src; f16* dst; int u, w0, W;
        if (b < 512) { u = b >> 2; w0 = (b & 3) * 32; W = 128; src = W1s; dst = W1P; }
        else         { u = b - 512; w0 = 0;           W = 32;  src = W2;  dst = W2P; }
        {
            int v = t >> 3, wq = t & 7;
            float4 f = *(const float4*)(src + (size_t)(u * 32 + v) * W + w0 + wq * 4);
            T[v * 36 + wq * 4 + 0] = (f16)f.x;
            T[v * 36 + wq * 4 + 1] = (f16)f.y;
            T[v * 36 + wq * 4 + 2] = (f16)f.z;
            T[v * 36 + wq * 4 + 3] = (f16)f.w;
        }
        __syncthreads();
        {
            int w = t >> 3, vr = t & 7;
            f16x4 o = { T[(vr * 4 + 0) * 36 + w], T[(vr * 4 + 1) * 36 + w],
                        T[(vr * 4 + 2) * 36 + w], T[(vr * 4 + 3) * 36 + w] };
            *(f16x4*)(dst + (size_t)u * (W * 32) + (size_t)(w0 + w) * 32 + vr * 4) = o;
        }
    } else if (b < 1152) {
        // s cast: 8192 x 128, 8 elems/thread
        int j = (b - 640) * 256 + t;
        int n = j >> 4, c = j & 15;
        float4 a  = *(const float4*)(node_vec + (size_t)n * 480 + c * 8);
        float4 bb = *(const float4*)(node_vec + (size_t)n * 480 + c * 8 + 4);
        f16x8 ev = { (f16)a.x, (f16)a.y, (f16)a.z, (f16)a.w,
                     (f16)bb.x, (f16)bb.y, (f16)bb.z, (f16)bb.w };
        *(f16x8*)(s_f16 + (size_t)n * 128 + c * 8) = ev;
    } else {
        // attr cast: 8192 x 32, 8 elems/thread
        int j = (b - 1152) * 256 + t;
        int n = j >> 2, c = j & 3;
        float4 a  = *(const float4*)(attr + (size_t)n * 32 + c * 8);
        float4 bb = *(const float4*)(attr + (size_t)n * 32 + c * 8 + 4);
        f16x8 ev = { (f16)a.x, (f16)a.y, (f16)a.z, (f16)a.w,
                     (f16)bb.x, (f16)bb.y, (f16)bb.z, (f16)bb.w };
        *(f16x8*)(attr_f16 + (size_t)n * 32 + c * 8) = ev;
    }
}

// ---------------------------------------------------------------------------
// Fused: GEMM1 (P-form, M=8192,N=128,K=4096) -> silu -> GEMM2 (P-form, N=32,
// K=4096, waves split K) -> head MLP.  One block = 32 nodes, 512 thr, 8 waves.
// B fragments read directly from global (L2-broadcast), depth-4 reg prefetch.
// ---------------------------------------------------------------------------
__global__ __launch_bounds__(512) void fused_kernel(
    const f16* __restrict__ s_f16, const f16* __restrict__ attr_f16,
    const f16* __restrict__ W1P, const f16* __restrict__ W2P,
    const float* __restrict__ b1s, const float* __restrict__ b2,
    const float* __restrict__ W3, const float* __restrict__ b3,
    const float* __restrict__ W4, const float* __restrict__ b4,
    float* __restrict__ out)
{
    __shared__ alignas(16) f16 s_lds[32 * 136];
    __shared__ alignas(16) f16 sact_lds[32 * 136];
    __shared__ alignas(16) float W3_lds[32 * 36];
    __shared__ alignas(16) float h_lds[2][32 * 36];

    const int t = threadIdx.x;
    const int n0 = blockIdx.x * 32;
    const int wv = t >> 6, l = t & 63, lr = l & 15, q = l >> 4;

    // stage s tile (32 x 128 f16, padded rows of 136) : 512 x 16B
    { int r = t >> 4, pt = t & 15;
      *(uint4*)(s_lds + r * 136 + pt * 8) =
          *(const uint4*)(s_f16 + (size_t)(n0 + r) * 128 + pt * 8); }
    // stage W3 (32 x 32 f32, stride 36)
    if (t < 256) { int i = t >> 3, j = (t & 7) * 4;
      *(f32x4*)(W3_lds + i * 36 + j) = *(const f32x4*)(W3 + i * 32 + j); }

    // attr fragments (K-invariant): attrh[mt][kk] = attr[n0+16mt+lr][q*8+2kk..+1]
    f16x2 attrh[2][4];
    #pragma unroll
    for (int mt = 0; mt < 2; ++mt)
        #pragma unroll
        for (int kk = 0; kk < 4; ++kk)
            attrh[mt][kk] = *(const f16x2*)(attr_f16 +
                (size_t)(n0 + 16 * mt + lr) * 32 + q * 8 + kk * 2);

    __syncthreads();

    // ================= GEMM1 =================
    // wave wv owns output cols 16*wv+lr; B frag = W1P[c][col][q*8..+7]
    const f16* Bbase = W1P + (16 * wv + lr) * 32 + q * 8;
    f16x8 bfrag[4];
    #pragma unroll
    for (int i = 0; i < 4; ++i) bfrag[i] = *(const f16x8*)(Bbase + i * 4096);
    f16 sv[2][2];
    #pragma unroll
    for (int pp = 0; pp < 2; ++pp) {
        sv[pp][0] = s_lds[lr * 136 + pp];
        sv[pp][1] = s_lds[(16 + lr) * 136 + pp];
    }

    f32x4 acc0 = {0.f, 0.f, 0.f, 0.f}, acc1 = {0.f, 0.f, 0.f, 0.f};
    #pragma unroll 4
    for (int c = 0; c < 128; ++c) {
        f16x8 bf = bfrag[c & 3];
        int cn = (c + 4 < 128) ? c + 4 : 127;
        bfrag[c & 3] = *(const f16x8*)(Bbase + (size_t)cn * 4096);
        f16 s0 = sv[c & 1][0], s1 = sv[c & 1][1];
        int cs = (c + 2 < 128) ? c + 2 : 127;
        sv[c & 1][0] = s_lds[lr * 136 + cs];
        sv[c & 1][1] = s_lds[(16 + lr) * 136 + cs];
        f16x2 s02 = {s0, s0}, s12 = {s1, s1};
        f16x8 a0, a1;
        #pragma unroll
        for (int kk = 0; kk < 4; ++kk) {
            f16x2 p0 = s02 * attrh[0][kk];
            f16x2 p1 = s12 * attrh[1][kk];
            a0[2 * kk] = p0[0]; a0[2 * kk + 1] = p0[1];
            a1[2 * kk] = p1[0]; a1[2 * kk + 1] = p1[1];
        }
        acc0 = __builtin_amdgcn_mfma_f32_16x16x32_f16(a0, bf, acc0, 0, 0, 0);
        acc1 = __builtin_amdgcn_mfma_f32_16x16x32_f16(a1, bf, acc1, 0, 0, 0);
    }

    // epilogue: scale, bias, silu -> sact_lds (f16)
    {
        float b1v = b1s[16 * wv + lr];
        #pragma unroll
        for (int reg = 0; reg < 4; ++reg) {
            float v0 = acc0[reg] * 0.015625f + b1v;
            float v1 = acc1[reg] * 0.015625f + b1v;
            float g0 = v0 / (1.f + __expf(-v0));
            float g1 = v1 / (1.f + __expf(-v1));
            sact_lds[(q * 4 + reg) * 136 + 16 * wv + lr] = (f16)g0;
            sact_lds[(16 + q * 4 + reg) * 136 + 16 * wv + lr] = (f16)g1;
        }
    }
    __syncthreads();

    // ================= GEMM2 =================
    // waves: wm,wn in {0,1}, kh = K-half.  B frag = W2P[c][16wn+lr][q*8..+7]
    const int wm = wv & 1, wn = (wv >> 1) & 1, kh = wv >> 2;
    f16x2 aw[4];
    #pragma unroll
    for (int kk = 0; kk < 4; ++kk) aw[kk] = wm ? attrh[1][kk] : attrh[0][kk];

    const f16* B2base = W2P + (size_t)kh * 64 * 1024 + (16 * wn + lr) * 32 + q * 8;
    const int srow = (16 * wm + lr) * 136 + kh * 64;
    f16x8 b2frag[4];
    #pragma unroll
    for (int i = 0; i < 4; ++i) b2frag[i] = *(const f16x8*)(B2base + i * 1024);
    f16 sv2[2];
    sv2[0] = sact_lds[srow + 0];
    sv2[1] = sact_lds[srow + 1];

    f32x4 acc2 = {0.f, 0.f, 0.f, 0.f};
    #pragma unroll 4
    for (int cc = 0; cc < 64; ++cc) {
        f16x8 bf = b2frag[cc & 3];
        int cn = (cc + 4 < 64) ? cc + 4 : 63;
        b2frag[cc & 3] = *(const f16x8*)(B2base + (size_t)cn * 1024);
        f16 s0 = sv2[cc & 1];
        int cs = (cc + 2 < 64) ? cc + 2 : 63;
        sv2[cc & 1] = sact_lds[srow + cs];
        f16x2 ss = {s0, s0};
        f16x8 a0;
        #pragma unroll
        for (int kk = 0; kk < 4; ++kk) {
            f16x2 p = ss * aw[kk];
            a0[2 * kk] = p[0]; a0[2 * kk + 1] = p[1];
        }
        acc2 = __builtin_amdgcn_mfma_f32_16x16x32_f16(a0, bf, acc2, 0, 0, 0);
    }
    {
        float b2v = (kh == 0) ? b2[16 * wn + lr] : 0.f;
        #pragma unroll
        for (int reg = 0; reg < 4; ++reg)
            h_lds[kh][(16 * wm + q * 4 + reg) * 36 + 16 * wn + lr] =
                acc2[reg] * 0.015625f + b2v;
    }
    __syncthreads();

    // ================= head =================
    {
        int hn = t >> 4, j0 = (t & 15) * 2;
        float a0 = 0.f, a1 = 0.f;
        #pragma unroll
        for (int i = 0; i < 32; ++i) {
            float hv = h_lds[0][hn * 36 + i] + h_lds[1][hn * 36 + i];
            a0 += hv * W3_lds[i * 36 + j0];
            a1 += hv * W3_lds[i * 36 + j0 + 1];
        }
        const float inv = 0.17677669529663687f;  // 1/sqrt(32)
        float t0 = a0 * inv + b3[j0];
        float t1 = a1 * inv + b3[j0 + 1];
        float g0 = t0 / (1.f + __expf(-t0));
        float g1 = t1 / (1.f + __expf(-t1));
        float p = g0 * W4[j0] * inv + g1 * W4[j0 + 1] * inv;
        p += __shfl_xor(p, 1);
        p += __shfl_xor(p, 2);
        p += __shfl_xor(p, 4);
        p += __shfl_xor(p, 8);
        if ((t & 15) == 0) out[n0 + hn] = p + b4[0];
    }
}

// ---------------------------------------------------------------------------
extern "C" void kernel_launch(void* const* d_in, const int* in_sizes, int n_in,
                              void* d_out, int out_size, void* d_ws, size_t ws_size,
                              hipStream_t stream)
{
    const float* node_vec = (const float*)d_in[0];
    const float* attr     = (const float*)d_in[1];
    const float* W1s      = (const float*)d_in[2];
    const float* b1s      = (const float*)d_in[3];
    // d_in[4..7] (W1g,b1g,W1v1,W1v2) are dead code w.r.t. pred_energy
    const float* W2       = (const float*)d_in[8];
    const float* b2       = (const float*)d_in[9];
    const float* W3       = (const float*)d_in[10];
    const float* b3       = (const float*)d_in[11];
    const float* W4       = (const float*)d_in[12];
    const float* b4       = (const float*)d_in[13];
    float* out = (float*)d_out;

    char* ws = (char*)d_ws;
    f16* s_f16    = (f16*)(ws);                    // 8192*128*2 = 2 MiB
    f16* attr_f16 = (f16*)(ws + (2u << 20));       // 8192*32*2  = 512 KiB
    f16* W1P      = (f16*)(ws + (2560u << 10));    // 128*128*32*2 = 1 MiB
    f16* W2P      = (f16*)(ws + (3584u << 10));    // 128*32*32*2  = 256 KiB

    prep_kernel<<<1280, 256, 0, stream>>>(node_vec, attr, W1s, W2,
                                          s_f16, attr_f16, W1P, W2P);
    fused_kernel<<<256, 512, 0, stream>>>(s_f16, attr_f16, W1P, W2P,
                                          b1s, b2, W3, b3, W4, b4, out);
}